// Round 4
// baseline (1141.756 us; speedup 1.0000x reference)
//
#include <hip/hip_runtime.h>

#define HIDDEN 64
#define BETA 0.01f
#define GAMMA 0.01f

#define BUCKET_SHIFT 7                 // 128 users per bucket
#define BUCKET_W     (1 << BUCKET_SHIFT)
#define TILE_E       12288             // entries per partition tile (48/thread)
#define ACC_ILP      8                 // entries in flight per wave in accumulate

// ---------------------------------------------------------------------------
// Encode phase A: H = features @ W_enc + b_enc   (thread per output element)
// ---------------------------------------------------------------------------
__global__ void h_kernel(const float* __restrict__ features,
                         const float* __restrict__ W_enc,
                         const float* __restrict__ b_enc,
                         float* __restrict__ H,
                         int num_movies, int in_feats) {
    const int tid = blockIdx.x * blockDim.x + threadIdx.x;
    const int j = tid & 63;
    const int m = tid >> 6;
    if (m >= num_movies) return;

    const float* frow = features + (size_t)m * in_feats;
    float a0 = 0.0f, a1 = 0.0f, a2 = 0.0f, a3 = 0.0f;
    #pragma unroll 8
    for (int f = 0; f < in_feats; f += 4) {
        const float4 fv = *(const float4*)(frow + f);
        a0 = fmaf(fv.x, W_enc[(f + 0) * HIDDEN + j], a0);
        a1 = fmaf(fv.y, W_enc[(f + 1) * HIDDEN + j], a1);
        a2 = fmaf(fv.z, W_enc[(f + 2) * HIDDEN + j], a2);
        a3 = fmaf(fv.w, W_enc[(f + 3) * HIDDEN + j], a3);
    }
    H[(size_t)m * HIDDEN + j] = (a0 + a1) + (a2 + a3) + b_enc[j];
}

// ---------------------------------------------------------------------------
// Encode phase B: P = H @ W_p, Q = H @ W_q + BETA regularizer.
// ---------------------------------------------------------------------------
__global__ void pq_kernel(const float* __restrict__ H,
                          const float* __restrict__ W_p,
                          const float* __restrict__ W_q,
                          float* __restrict__ P,
                          float* __restrict__ Q,
                          float* __restrict__ out_loss,
                          int num_movies) {
    const int tid = blockIdx.x * blockDim.x + threadIdx.x;
    const int j = tid & 63;
    const int m = tid >> 6;
    float reg = 0.0f;

    if (m < num_movies) {
        const float* hrow = H + (size_t)m * HIDDEN;
        float p0 = 0.0f, p1 = 0.0f, p2 = 0.0f, p3 = 0.0f;
        float q0 = 0.0f, q1 = 0.0f, q2 = 0.0f, q3 = 0.0f;
        #pragma unroll 4
        for (int f = 0; f < HIDDEN; f += 4) {
            const float4 hv = *(const float4*)(hrow + f);
            p0 = fmaf(hv.x, W_p[(f + 0) * HIDDEN + j], p0);
            p1 = fmaf(hv.y, W_p[(f + 1) * HIDDEN + j], p1);
            p2 = fmaf(hv.z, W_p[(f + 2) * HIDDEN + j], p2);
            p3 = fmaf(hv.w, W_p[(f + 3) * HIDDEN + j], p3);
            q0 = fmaf(hv.x, W_q[(f + 0) * HIDDEN + j], q0);
            q1 = fmaf(hv.y, W_q[(f + 1) * HIDDEN + j], q1);
            q2 = fmaf(hv.z, W_q[(f + 2) * HIDDEN + j], q2);
            q3 = fmaf(hv.w, W_q[(f + 3) * HIDDEN + j], q3);
        }
        const float p = (p0 + p1) + (p2 + p3);
        const float q = (q0 + q1) + (q2 + q3);
        P[(size_t)m * HIDDEN + j] = p;
        Q[(size_t)m * HIDDEN + j] = q;
        reg = p * p + q * q;
    }

    for (int off = 32; off; off >>= 1) reg += __shfl_down(reg, off);
    __shared__ float s_part[16];
    const int wave = threadIdx.x >> 6;
    const int lane = threadIdx.x & 63;
    if (lane == 0) s_part[wave] = reg;
    __syncthreads();
    if (threadIdx.x == 0) {
        float t = 0.0f;
        const int nw = blockDim.x >> 6;
        for (int w = 0; w < nw; ++w) t += s_part[w];
        atomicAdd(out_loss, 0.5f * BETA * t);
    }
}

// ---------------------------------------------------------------------------
// Partition phase A: per-tile bucket histogram (LDS), tileHist[b*nT + t].
// ---------------------------------------------------------------------------
__global__ void tilehist_kernel(const int* __restrict__ rows, int nnz,
                                int nbuckets, int ntiles,
                                unsigned* __restrict__ tileHist) {
    extern __shared__ unsigned hist[];          // nbuckets
    const int t = blockIdx.x;
    const int tid = threadIdx.x;
    for (int i = tid; i < nbuckets; i += blockDim.x) hist[i] = 0;
    __syncthreads();

    const int base = t * TILE_E;
    const int kmax = TILE_E / 256;
    #pragma unroll 4
    for (int k = 0; k < kmax; ++k) {
        const int e = base + k * 256 + tid;
        if (e < nnz) atomicAdd(&hist[rows[e] >> BUCKET_SHIFT], 1u);
    }
    __syncthreads();
    for (int i = tid; i < nbuckets; i += blockDim.x)
        tileHist[(size_t)i * ntiles + t] = hist[i];
}

// ---------------------------------------------------------------------------
// Scan step 1: per-chunk (256) sums.
// ---------------------------------------------------------------------------
__global__ void scan1_kernel(const unsigned* __restrict__ counts, int n,
                             unsigned* __restrict__ block_sums) {
    __shared__ unsigned s[256];
    const int t = threadIdx.x;
    const int i = blockIdx.x * 256 + t;
    unsigned x = (i < n) ? counts[i] : 0u;
    s[t] = x;
    __syncthreads();
    for (int off = 128; off; off >>= 1) {
        if (t < off) s[t] += s[t + off];
        __syncthreads();
    }
    if (t == 0) block_sums[blockIdx.x] = s[0];
}

// ---------------------------------------------------------------------------
// Scan step 2: single-block exclusive scan of chunk sums (nb <= 256).
// Thread 0 writes offs[n] = nnz (total).
// ---------------------------------------------------------------------------
__global__ void scan2_kernel(unsigned* __restrict__ block_sums, int nb,
                             unsigned* __restrict__ block_offsets,
                             unsigned* __restrict__ offs, int n, int nnz) {
    __shared__ unsigned s[256];
    const int t = threadIdx.x;
    unsigned x = (t < nb) ? block_sums[t] : 0u;
    s[t] = x;
    __syncthreads();
    for (int off = 1; off < 256; off <<= 1) {
        unsigned v = (t >= off) ? s[t - off] : 0u;
        __syncthreads();
        s[t] += v;
        __syncthreads();
    }
    if (t < nb) block_offsets[t] = s[t] - x;   // exclusive
    if (t == 0) offs[n] = (unsigned)nnz;
}

// ---------------------------------------------------------------------------
// Scan step 3: per-chunk exclusive scan + chunk offset -> offs.
// ---------------------------------------------------------------------------
__global__ void scan3_kernel(const unsigned* __restrict__ counts, int n,
                             const unsigned* __restrict__ block_offsets,
                             unsigned* __restrict__ offs) {
    __shared__ unsigned s[256];
    const int t = threadIdx.x;
    const int i = blockIdx.x * 256 + t;
    unsigned x = (i < n) ? counts[i] : 0u;
    s[t] = x;
    __syncthreads();
    for (int off = 1; off < 256; off <<= 1) {
        unsigned v = (t >= off) ? s[t - off] : 0u;
        __syncthreads();
        s[t] += v;
        __syncthreads();
    }
    if (i < n) offs[i] = block_offsets[blockIdx.x] + s[t] - x;
}

// ---------------------------------------------------------------------------
// Partition phase C: atomic-free (globally) scatter into bucket-major order.
// Local rank via LDS returning atomic; dst = offs[b*nT + t] + lrank.
// Entry packed: key = (localu << 15) | col  (col < 32768), val bits.
// ---------------------------------------------------------------------------
__global__ void partition_kernel(const int* __restrict__ rows,
                                 const int* __restrict__ cols,
                                 const float* __restrict__ vals, int nnz,
                                 int nbuckets, int ntiles,
                                 const unsigned* __restrict__ offs,
                                 uint2* __restrict__ pairs) {
    extern __shared__ unsigned smem[];          // hist[nb] then lofs[nb]
    unsigned* hist = smem;
    unsigned* lofs = smem + nbuckets;
    const int t = blockIdx.x;
    const int tid = threadIdx.x;
    for (int i = tid; i < nbuckets; i += blockDim.x) {
        hist[i] = 0;
        lofs[i] = offs[(size_t)i * ntiles + t];
    }
    __syncthreads();

    const int base = t * TILE_E;
    const int kmax = TILE_E / 256;
    #pragma unroll 4
    for (int k = 0; k < kmax; ++k) {
        const int e = base + k * 256 + tid;
        if (e < nnz) {
            const int r = rows[e];
            const int b = r >> BUCKET_SHIFT;
            const unsigned lrank = atomicAdd(&hist[b], 1u);
            const unsigned dst = lofs[b] + lrank;
            const unsigned key = ((unsigned)(r & (BUCKET_W - 1)) << 15) |
                                 (unsigned)cols[e];
            pairs[dst] = make_uint2(key, __float_as_uint(vals[e]));
        }
    }
}

// ---------------------------------------------------------------------------
// Phase D: bucket accumulate. One WG per bucket (128 users), LDS acc tile.
//   acc[localu][k] += val * P[col*64 + k]   via LDS f32 atomics.
// 4 waves x ACC_ILP entries in flight for MLP.
// ---------------------------------------------------------------------------
__global__ void __launch_bounds__(256)
accumulate_kernel(const uint2* __restrict__ pairs,
                  const unsigned* __restrict__ offs,
                  const float* __restrict__ P,
                  float* __restrict__ user_emb,
                  float* __restrict__ user_deg,
                  int nu, int ntiles, int nbuckets) {
    __shared__ float acc[BUCKET_W][HIDDEN];     // 32 KB
    __shared__ float degs[BUCKET_W];

    const int b = blockIdx.x;
    const int tid = threadIdx.x;
    const int lane = tid & 63;
    const int wave = tid >> 6;

    for (int i = tid; i < BUCKET_W * HIDDEN; i += 256)
        ((float*)acc)[i] = 0.0f;
    for (int i = tid; i < BUCKET_W; i += 256) degs[i] = 0.0f;
    __syncthreads();

    const int bstart = (int)offs[(size_t)b * ntiles];
    const int bend   = (int)offs[(size_t)(b + 1) * ntiles];

    for (int base = bstart + wave * ACC_ILP; base < bend; base += 4 * ACC_ILP) {
        uint2 ent[ACC_ILP];
        float pv[ACC_ILP];
        #pragma unroll
        for (int j = 0; j < ACC_ILP; ++j) {
            ent[j] = (base + j < bend) ? pairs[base + j] : make_uint2(0u, 0u);
        }
        #pragma unroll
        for (int j = 0; j < ACC_ILP; ++j) {
            const unsigned col = ent[j].x & 0x7fffu;
            pv[j] = P[(size_t)col * HIDDEN + lane];
        }
        #pragma unroll
        for (int j = 0; j < ACC_ILP; ++j) {
            const unsigned lu = ent[j].x >> 15;
            const float v = __uint_as_float(ent[j].y);
            atomicAdd(&acc[lu][lane], v * pv[j]);
            if (lane == 0) atomicAdd(&degs[lu], v);
        }
    }
    __syncthreads();

    // writeout: thread (wave, lane) covers users wave, wave+4, ...
    for (int u = wave; u < BUCKET_W; u += 4) {
        const int gu = b * BUCKET_W + u;
        if (gu < nu) {
            user_emb[(size_t)gu * HIDDEN + lane] = acc[u][lane];
            if (lane == 0) user_deg[gu] = degs[u];
        }
    }
}

// ---------------------------------------------------------------------------
// Pair loss. One thread per positive pair.
// ---------------------------------------------------------------------------
__global__ void loss_kernel(const float* __restrict__ user_emb,
                            const float* __restrict__ user_deg,
                            const float* __restrict__ Q,
                            const float* __restrict__ b_u,
                            const float* __restrict__ b_i,
                            const int* __restrict__ rows,
                            const int* __restrict__ cols,
                            const int* __restrict__ pos_idx,
                            const int* __restrict__ neg_item_idx,
                            int num_pos, int S,
                            float* __restrict__ out_loss) {
    const int p = blockIdx.x * blockDim.x + threadIdx.x;
    float acc = 0.0f;

    if (p < num_pos) {
        const int e = pos_idx[p];
        const int u = rows[e];
        const int ii = cols[e];
        const float invdeg = 1.0f / user_deg[u];

        float ue[HIDDEN];
        const float4* uep = (const float4*)(user_emb + (size_t)u * HIDDEN);
        #pragma unroll
        for (int k = 0; k < HIDDEN / 4; ++k) {
            float4 t4 = uep[k];
            ue[4 * k + 0] = t4.x * invdeg;
            ue[4 * k + 1] = t4.y * invdeg;
            ue[4 * k + 2] = t4.z * invdeg;
            ue[4 * k + 3] = t4.w * invdeg;
        }
        const float bu = b_u[u];

        const float4* qp = (const float4*)(Q + (size_t)ii * HIDDEN);
        float dot = 0.0f;
        #pragma unroll
        for (int k = 0; k < HIDDEN / 4; ++k) {
            float4 t4 = qp[k];
            dot = fmaf(ue[4 * k + 0], t4.x, dot);
            dot = fmaf(ue[4 * k + 1], t4.y, dot);
            dot = fmaf(ue[4 * k + 2], t4.z, dot);
            dot = fmaf(ue[4 * k + 3], t4.w, dot);
        }
        const float r = bu + b_i[ii] + dot;

        for (int s = 0; s < S; ++s) {
            const int j = neg_item_idx[(size_t)p * S + s];
            const float4* qn = (const float4*)(Q + (size_t)j * HIDDEN);
            float dn = 0.0f;
            #pragma unroll
            for (int k = 0; k < HIDDEN / 4; ++k) {
                float4 t4 = qn[k];
                dn = fmaf(ue[4 * k + 0], t4.x, dn);
                dn = fmaf(ue[4 * k + 1], t4.y, dn);
                dn = fmaf(ue[4 * k + 2], t4.z, dn);
                dn = fmaf(ue[4 * k + 3], t4.w, dn);
            }
            const float nr = bu + b_i[j] + dn;
            const float diff = 1.0f - (r - nr);
            acc += 0.5f * diff * diff;
        }
    }

    for (int off = 32; off; off >>= 1) acc += __shfl_down(acc, off);
    __shared__ float s_part[16];
    const int wave = threadIdx.x >> 6;
    const int lane = threadIdx.x & 63;
    if (lane == 0) s_part[wave] = acc;
    __syncthreads();
    if (threadIdx.x == 0) {
        float t = 0.0f;
        const int nw = blockDim.x >> 6;
        for (int w = 0; w < nw; ++w) t += s_part[w];
        atomicAdd(out_loss, t);
    }
}

// ---------------------------------------------------------------------------
// Bias regularizer 0.5*GAMMA*(sum b_u^2 + sum b_i^2)
// ---------------------------------------------------------------------------
__global__ void bias_reg_kernel(const float* __restrict__ b_u, int nu,
                                const float* __restrict__ b_i, int ni,
                                float* __restrict__ out_loss) {
    const int tid = blockIdx.x * blockDim.x + threadIdx.x;
    const int stride = gridDim.x * blockDim.x;
    const int n = nu + ni;
    float acc = 0.0f;
    for (int x = tid; x < n; x += stride) {
        float v = (x < nu) ? b_u[x] : b_i[x - nu];
        acc += v * v;
    }
    for (int off = 32; off; off >>= 1) acc += __shfl_down(acc, off);
    __shared__ float s_part[16];
    const int wave = threadIdx.x >> 6;
    const int lane = threadIdx.x & 63;
    if (lane == 0) s_part[wave] = acc;
    __syncthreads();
    if (threadIdx.x == 0) {
        float t = 0.0f;
        const int nw = blockDim.x >> 6;
        for (int w = 0; w < nw; ++w) t += s_part[w];
        atomicAdd(out_loss, 0.5f * GAMMA * t);
    }
}

// ---------------------------------------------------------------------------
extern "C" void kernel_launch(void* const* d_in, const int* in_sizes, int n_in,
                              void* d_out, int out_size, void* d_ws, size_t ws_size,
                              hipStream_t stream) {
    const float* features     = (const float*)d_in[0];
    const float* W_enc        = (const float*)d_in[1];
    const float* b_enc        = (const float*)d_in[2];
    const float* W_p          = (const float*)d_in[3];
    const float* W_q          = (const float*)d_in[4];
    const float* b_u          = (const float*)d_in[5];
    const float* b_i          = (const float*)d_in[6];
    const float* vals         = (const float*)d_in[7];
    const int*   rows         = (const int*)d_in[8];
    const int*   cols         = (const int*)d_in[9];
    const int*   pos_idx      = (const int*)d_in[10];
    const int*   neg_item_idx = (const int*)d_in[11];

    const int num_users  = in_sizes[5];
    const int num_movies = in_sizes[6];
    const int in_feats   = in_sizes[0] / num_movies;   // 128
    const int nnz        = in_sizes[7];
    const int num_pos    = in_sizes[10];
    const int S          = in_sizes[11] / num_pos;     // 5

    const int nbuckets = (num_users + BUCKET_W - 1) >> BUCKET_SHIFT;  // 391
    const int ntiles   = (nnz + TILE_E - 1) / TILE_E;                 // 163
    const int scanN    = nbuckets * ntiles;                           // 63733
    const int nchunks  = (scanN + 255) / 256;                         // 249 (<=256)

    // workspace layout (256B-aligned)
    auto align256 = [](size_t x) { return (x + 255) & ~(size_t)255; };
    char* ws = (char*)d_ws;
    size_t off = 0;
    float* P        = (float*)(ws + off); off += align256((size_t)num_movies * HIDDEN * 4);
    float* Q        = (float*)(ws + off); off += align256((size_t)num_movies * HIDDEN * 4);
    float* H        = (float*)(ws + off); off += align256((size_t)num_movies * HIDDEN * 4);
    float* user_emb = (float*)(ws + off); off += align256((size_t)num_users * HIDDEN * 4);
    float* user_deg = (float*)(ws + off); off += align256((size_t)num_users * 4);
    unsigned* tileHist      = (unsigned*)(ws + off); off += align256((size_t)(scanN + 1) * 4);
    unsigned* block_sums    = (unsigned*)(ws + off); off += align256(256 * 4);
    unsigned* block_offsets = (unsigned*)(ws + off); off += align256(256 * 4);
    uint2* pairs    = (uint2*)(ws + off); off += align256((size_t)nnz * 8);

    float* out = (float*)d_out;
    hipMemsetAsync(out, 0, sizeof(float), stream);

    const int enc_blocks = (num_movies * 64 + 255) / 256;
    h_kernel<<<enc_blocks, 256, 0, stream>>>(features, W_enc, b_enc, H,
                                             num_movies, in_feats);
    pq_kernel<<<enc_blocks, 256, 0, stream>>>(H, W_p, W_q, P, Q, out, num_movies);

    const size_t hist_lds = (size_t)nbuckets * 4;
    tilehist_kernel<<<ntiles, 256, hist_lds, stream>>>(rows, nnz, nbuckets,
                                                       ntiles, tileHist);
    scan1_kernel<<<nchunks, 256, 0, stream>>>(tileHist, scanN, block_sums);
    scan2_kernel<<<1, 256, 0, stream>>>(block_sums, nchunks, block_offsets,
                                        tileHist /*unused*/, scanN, nnz);
    // note: scan2 writes offs[scanN] = nnz into tileHist array? No -- offs IS
    // a separate view: we scan tileHist in-place is unsafe (scan3 re-reads
    // counts). Use two arrays: counts = tileHist, offs = tileHist2.
    // (handled below -- see offs buffer)
    {} // layout continues:
    unsigned* offs = (unsigned*)(ws + off); off += align256((size_t)(scanN + 1) * 4);
    scan2_kernel<<<1, 256, 0, stream>>>(block_sums, nchunks, block_offsets,
                                        offs, scanN, nnz);
    scan3_kernel<<<nchunks, 256, 0, stream>>>(tileHist, scanN, block_offsets, offs);

    const size_t part_lds = (size_t)nbuckets * 8;  // hist + lofs
    partition_kernel<<<ntiles, 256, part_lds, stream>>>(rows, cols, vals, nnz,
                                                        nbuckets, ntiles, offs,
                                                        pairs);

    accumulate_kernel<<<nbuckets, 256, 0, stream>>>(pairs, offs, P, user_emb,
                                                    user_deg, num_users,
                                                    ntiles, nbuckets);

    loss_kernel<<<(num_pos + 255) / 256, 256, 0, stream>>>(
        user_emb, user_deg, Q, b_u, b_i, rows, cols, pos_idx, neg_item_idx,
        num_pos, S, out);

    bias_reg_kernel<<<128, 256, 0, stream>>>(b_u, num_users, b_i, num_movies, out);
}

// Round 5
// 1117.507 us; speedup vs baseline: 1.0217x; 1.0217x over previous
//
#include <hip/hip_runtime.h>

#define HIDDEN 64
#define BETA 0.01f
#define GAMMA 0.01f

#define BUCKET_SHIFT 6                 // 64 users per bucket
#define BUCKET_W     (1 << BUCKET_SHIFT)
#define TILE_E       8192              // entries per partition tile (32/thread)
#define ACC_ILP      8                 // entries in flight per wave in accumulate

// ---------------------------------------------------------------------------
// Encode phase A: H = features @ W_enc + b_enc   (thread per output element)
// ---------------------------------------------------------------------------
__global__ void h_kernel(const float* __restrict__ features,
                         const float* __restrict__ W_enc,
                         const float* __restrict__ b_enc,
                         float* __restrict__ H,
                         int num_movies, int in_feats) {
    const int tid = blockIdx.x * blockDim.x + threadIdx.x;
    const int j = tid & 63;
    const int m = tid >> 6;
    if (m >= num_movies) return;

    const float* frow = features + (size_t)m * in_feats;
    float a0 = 0.0f, a1 = 0.0f, a2 = 0.0f, a3 = 0.0f;
    #pragma unroll 8
    for (int f = 0; f < in_feats; f += 4) {
        const float4 fv = *(const float4*)(frow + f);
        a0 = fmaf(fv.x, W_enc[(f + 0) * HIDDEN + j], a0);
        a1 = fmaf(fv.y, W_enc[(f + 1) * HIDDEN + j], a1);
        a2 = fmaf(fv.z, W_enc[(f + 2) * HIDDEN + j], a2);
        a3 = fmaf(fv.w, W_enc[(f + 3) * HIDDEN + j], a3);
    }
    H[(size_t)m * HIDDEN + j] = (a0 + a1) + (a2 + a3) + b_enc[j];
}

// ---------------------------------------------------------------------------
// Encode phase B: P = H @ W_p, Q = H @ W_q + BETA regularizer.
// ---------------------------------------------------------------------------
__global__ void pq_kernel(const float* __restrict__ H,
                          const float* __restrict__ W_p,
                          const float* __restrict__ W_q,
                          float* __restrict__ P,
                          float* __restrict__ Q,
                          float* __restrict__ out_loss,
                          int num_movies) {
    const int tid = blockIdx.x * blockDim.x + threadIdx.x;
    const int j = tid & 63;
    const int m = tid >> 6;
    float reg = 0.0f;

    if (m < num_movies) {
        const float* hrow = H + (size_t)m * HIDDEN;
        float p0 = 0.0f, p1 = 0.0f, p2 = 0.0f, p3 = 0.0f;
        float q0 = 0.0f, q1 = 0.0f, q2 = 0.0f, q3 = 0.0f;
        #pragma unroll 4
        for (int f = 0; f < HIDDEN; f += 4) {
            const float4 hv = *(const float4*)(hrow + f);
            p0 = fmaf(hv.x, W_p[(f + 0) * HIDDEN + j], p0);
            p1 = fmaf(hv.y, W_p[(f + 1) * HIDDEN + j], p1);
            p2 = fmaf(hv.z, W_p[(f + 2) * HIDDEN + j], p2);
            p3 = fmaf(hv.w, W_p[(f + 3) * HIDDEN + j], p3);
            q0 = fmaf(hv.x, W_q[(f + 0) * HIDDEN + j], q0);
            q1 = fmaf(hv.y, W_q[(f + 1) * HIDDEN + j], q1);
            q2 = fmaf(hv.z, W_q[(f + 2) * HIDDEN + j], q2);
            q3 = fmaf(hv.w, W_q[(f + 3) * HIDDEN + j], q3);
        }
        const float p = (p0 + p1) + (p2 + p3);
        const float q = (q0 + q1) + (q2 + q3);
        P[(size_t)m * HIDDEN + j] = p;
        Q[(size_t)m * HIDDEN + j] = q;
        reg = p * p + q * q;
    }

    for (int off = 32; off; off >>= 1) reg += __shfl_down(reg, off);
    __shared__ float s_part[16];
    const int wave = threadIdx.x >> 6;
    const int lane = threadIdx.x & 63;
    if (lane == 0) s_part[wave] = reg;
    __syncthreads();
    if (threadIdx.x == 0) {
        float t = 0.0f;
        const int nw = blockDim.x >> 6;
        for (int w = 0; w < nw; ++w) t += s_part[w];
        atomicAdd(out_loss, 0.5f * BETA * t);
    }
}

// ---------------------------------------------------------------------------
// Partition phase A: per-tile bucket histogram (LDS), tileHist[b*nT + t].
// ---------------------------------------------------------------------------
__global__ void tilehist_kernel(const int* __restrict__ rows, int nnz,
                                int nbuckets, int ntiles,
                                unsigned* __restrict__ tileHist) {
    extern __shared__ unsigned hist[];          // nbuckets
    const int t = blockIdx.x;
    const int tid = threadIdx.x;
    for (int i = tid; i < nbuckets; i += blockDim.x) hist[i] = 0;
    __syncthreads();

    const int base = t * TILE_E;
    const int kmax = TILE_E / 256;
    #pragma unroll 4
    for (int k = 0; k < kmax; ++k) {
        const int e = base + k * 256 + tid;
        if (e < nnz) atomicAdd(&hist[rows[e] >> BUCKET_SHIFT], 1u);
    }
    __syncthreads();
    for (int i = tid; i < nbuckets; i += blockDim.x)
        tileHist[(size_t)i * ntiles + t] = hist[i];
}

// ---------------------------------------------------------------------------
// Generic scan building blocks (3-level, up to 16M elements).
// ---------------------------------------------------------------------------
__global__ void chunksum_kernel(const unsigned* __restrict__ src, int n,
                                unsigned* __restrict__ sums) {
    __shared__ unsigned s[256];
    const int t = threadIdx.x;
    const int i = blockIdx.x * 256 + t;
    s[t] = (i < n) ? src[i] : 0u;
    __syncthreads();
    for (int off = 128; off; off >>= 1) {
        if (t < off) s[t] += s[t + off];
        __syncthreads();
    }
    if (t == 0) sums[blockIdx.x] = s[0];
}

// single-block exclusive scan of top-level sums (n2 <= 256); also writes the
// offs[] guard slot offs[scanN] = nnz.
__global__ void scantop_kernel(const unsigned* __restrict__ sums2, int n2,
                               unsigned* __restrict__ top_off,
                               unsigned* __restrict__ offs, int scanN, int nnz) {
    __shared__ unsigned s[256];
    const int t = threadIdx.x;
    unsigned x = (t < n2) ? sums2[t] : 0u;
    s[t] = x;
    __syncthreads();
    for (int off = 1; off < 256; off <<= 1) {
        unsigned v = (t >= off) ? s[t - off] : 0u;
        __syncthreads();
        s[t] += v;
        __syncthreads();
    }
    if (t < n2) top_off[t] = s[t] - x;          // exclusive
    if (t == 0) offs[scanN] = (unsigned)nnz;
}

// per-chunk exclusive scan + chunk offset. Safe for src == dst (block-local).
__global__ void exscan_kernel(const unsigned* __restrict__ src, int n,
                              const unsigned* __restrict__ chunk_off,
                              unsigned* __restrict__ dst) {
    __shared__ unsigned s[256];
    const int t = threadIdx.x;
    const int i = blockIdx.x * 256 + t;
    unsigned x = (i < n) ? src[i] : 0u;
    s[t] = x;
    __syncthreads();
    for (int off = 1; off < 256; off <<= 1) {
        unsigned v = (t >= off) ? s[t - off] : 0u;
        __syncthreads();
        s[t] += v;
        __syncthreads();
    }
    if (i < n) dst[i] = chunk_off[blockIdx.x] + s[t] - x;
}

// ---------------------------------------------------------------------------
// Partition phase C: scatter into bucket-major order, contiguous runs.
// Local rank via LDS returning atomic; dst = offs[b*nT + t] + lrank.
// Entry packed: key = (localu << 15) | col  (col < 32768, localu < 64).
// ---------------------------------------------------------------------------
__global__ void partition_kernel(const int* __restrict__ rows,
                                 const int* __restrict__ cols,
                                 const float* __restrict__ vals, int nnz,
                                 int nbuckets, int ntiles,
                                 const unsigned* __restrict__ offs,
                                 uint2* __restrict__ pairs) {
    extern __shared__ unsigned smem[];          // hist[nb] then lofs[nb]
    unsigned* hist = smem;
    unsigned* lofs = smem + nbuckets;
    const int t = blockIdx.x;
    const int tid = threadIdx.x;
    for (int i = tid; i < nbuckets; i += blockDim.x) {
        hist[i] = 0;
        lofs[i] = offs[(size_t)i * ntiles + t];
    }
    __syncthreads();

    const int base = t * TILE_E;
    const int kmax = TILE_E / 256;
    #pragma unroll 4
    for (int k = 0; k < kmax; ++k) {
        const int e = base + k * 256 + tid;
        if (e < nnz) {
            const int r = rows[e];
            const int b = r >> BUCKET_SHIFT;
            const unsigned lrank = atomicAdd(&hist[b], 1u);
            const unsigned dst = lofs[b] + lrank;
            const unsigned key = ((unsigned)(r & (BUCKET_W - 1)) << 15) |
                                 (unsigned)cols[e];
            pairs[dst] = make_uint2(key, __float_as_uint(vals[e]));
        }
    }
}

// ---------------------------------------------------------------------------
// Phase D: bucket accumulate. One WG per 64-user bucket, 16.6 KB LDS tile.
//   acc[localu][k] += val * P[col*64 + k]   via LDS f32 atomics.
// 782 WGs -> ~3 WG/CU, 12 waves/CU; 4 waves x ACC_ILP entries in flight.
// ---------------------------------------------------------------------------
__global__ void __launch_bounds__(256)
accumulate_kernel(const uint2* __restrict__ pairs,
                  const unsigned* __restrict__ offs,
                  const float* __restrict__ P,
                  float* __restrict__ user_emb,
                  float* __restrict__ user_deg,
                  int nu, int ntiles) {
    __shared__ float acc[BUCKET_W][HIDDEN];     // 16 KB
    __shared__ float degs[BUCKET_W];

    const int b = blockIdx.x;
    const int tid = threadIdx.x;
    const int lane = tid & 63;
    const int wave = tid >> 6;

    for (int i = tid; i < BUCKET_W * HIDDEN; i += 256)
        ((float*)acc)[i] = 0.0f;
    if (tid < BUCKET_W) degs[tid] = 0.0f;
    __syncthreads();

    const int bstart = (int)offs[(size_t)b * ntiles];
    const int bend   = (int)offs[(size_t)(b + 1) * ntiles];

    for (int base = bstart + wave * ACC_ILP; base < bend; base += 4 * ACC_ILP) {
        uint2 ent[ACC_ILP];
        float pv[ACC_ILP];
        #pragma unroll
        for (int j = 0; j < ACC_ILP; ++j) {
            ent[j] = (base + j < bend) ? pairs[base + j] : make_uint2(0u, 0u);
        }
        #pragma unroll
        for (int j = 0; j < ACC_ILP; ++j) {
            const unsigned col = ent[j].x & 0x7fffu;
            pv[j] = P[(size_t)col * HIDDEN + lane];
        }
        #pragma unroll
        for (int j = 0; j < ACC_ILP; ++j) {
            if (base + j < bend) {
                const unsigned lu = ent[j].x >> 15;
                const float v = __uint_as_float(ent[j].y);
                atomicAdd(&acc[lu][lane], v * pv[j]);
                if (lane == 0) atomicAdd(&degs[lu], v);
            }
        }
    }
    __syncthreads();

    // coalesced writeout: wave w covers users w, w+4, ...
    for (int u = wave; u < BUCKET_W; u += 4) {
        const int gu = b * BUCKET_W + u;
        if (gu < nu) {
            user_emb[(size_t)gu * HIDDEN + lane] = acc[u][lane];
            if (lane == 0) user_deg[gu] = degs[u];
        }
    }
}

// ---------------------------------------------------------------------------
// Pair loss. One thread per positive pair.
// ---------------------------------------------------------------------------
__global__ void loss_kernel(const float* __restrict__ user_emb,
                            const float* __restrict__ user_deg,
                            const float* __restrict__ Q,
                            const float* __restrict__ b_u,
                            const float* __restrict__ b_i,
                            const int* __restrict__ rows,
                            const int* __restrict__ cols,
                            const int* __restrict__ pos_idx,
                            const int* __restrict__ neg_item_idx,
                            int num_pos, int S,
                            float* __restrict__ out_loss) {
    const int p = blockIdx.x * blockDim.x + threadIdx.x;
    float acc = 0.0f;

    if (p < num_pos) {
        const int e = pos_idx[p];
        const int u = rows[e];
        const int ii = cols[e];
        const float invdeg = 1.0f / user_deg[u];

        float ue[HIDDEN];
        const float4* uep = (const float4*)(user_emb + (size_t)u * HIDDEN);
        #pragma unroll
        for (int k = 0; k < HIDDEN / 4; ++k) {
            float4 t4 = uep[k];
            ue[4 * k + 0] = t4.x * invdeg;
            ue[4 * k + 1] = t4.y * invdeg;
            ue[4 * k + 2] = t4.z * invdeg;
            ue[4 * k + 3] = t4.w * invdeg;
        }
        const float bu = b_u[u];

        const float4* qp = (const float4*)(Q + (size_t)ii * HIDDEN);
        float dot = 0.0f;
        #pragma unroll
        for (int k = 0; k < HIDDEN / 4; ++k) {
            float4 t4 = qp[k];
            dot = fmaf(ue[4 * k + 0], t4.x, dot);
            dot = fmaf(ue[4 * k + 1], t4.y, dot);
            dot = fmaf(ue[4 * k + 2], t4.z, dot);
            dot = fmaf(ue[4 * k + 3], t4.w, dot);
        }
        const float r = bu + b_i[ii] + dot;

        for (int s = 0; s < S; ++s) {
            const int j = neg_item_idx[(size_t)p * S + s];
            const float4* qn = (const float4*)(Q + (size_t)j * HIDDEN);
            float dn = 0.0f;
            #pragma unroll
            for (int k = 0; k < HIDDEN / 4; ++k) {
                float4 t4 = qn[k];
                dn = fmaf(ue[4 * k + 0], t4.x, dn);
                dn = fmaf(ue[4 * k + 1], t4.y, dn);
                dn = fmaf(ue[4 * k + 2], t4.z, dn);
                dn = fmaf(ue[4 * k + 3], t4.w, dn);
            }
            const float nr = bu + b_i[j] + dn;
            const float diff = 1.0f - (r - nr);
            acc += 0.5f * diff * diff;
        }
    }

    for (int off = 32; off; off >>= 1) acc += __shfl_down(acc, off);
    __shared__ float s_part[16];
    const int wave = threadIdx.x >> 6;
    const int lane = threadIdx.x & 63;
    if (lane == 0) s_part[wave] = acc;
    __syncthreads();
    if (threadIdx.x == 0) {
        float t = 0.0f;
        const int nw = blockDim.x >> 6;
        for (int w = 0; w < nw; ++w) t += s_part[w];
        atomicAdd(out_loss, t);
    }
}

// ---------------------------------------------------------------------------
// Bias regularizer 0.5*GAMMA*(sum b_u^2 + sum b_i^2)
// ---------------------------------------------------------------------------
__global__ void bias_reg_kernel(const float* __restrict__ b_u, int nu,
                                const float* __restrict__ b_i, int ni,
                                float* __restrict__ out_loss) {
    const int tid = blockIdx.x * blockDim.x + threadIdx.x;
    const int stride = gridDim.x * blockDim.x;
    const int n = nu + ni;
    float acc = 0.0f;
    for (int x = tid; x < n; x += stride) {
        float v = (x < nu) ? b_u[x] : b_i[x - nu];
        acc += v * v;
    }
    for (int off = 32; off; off >>= 1) acc += __shfl_down(acc, off);
    __shared__ float s_part[16];
    const int wave = threadIdx.x >> 6;
    const int lane = threadIdx.x & 63;
    if (lane == 0) s_part[wave] = acc;
    __syncthreads();
    if (threadIdx.x == 0) {
        float t = 0.0f;
        const int nw = blockDim.x >> 6;
        for (int w = 0; w < nw; ++w) t += s_part[w];
        atomicAdd(out_loss, 0.5f * GAMMA * t);
    }
}

// ---------------------------------------------------------------------------
extern "C" void kernel_launch(void* const* d_in, const int* in_sizes, int n_in,
                              void* d_out, int out_size, void* d_ws, size_t ws_size,
                              hipStream_t stream) {
    const float* features     = (const float*)d_in[0];
    const float* W_enc        = (const float*)d_in[1];
    const float* b_enc        = (const float*)d_in[2];
    const float* W_p          = (const float*)d_in[3];
    const float* W_q          = (const float*)d_in[4];
    const float* b_u          = (const float*)d_in[5];
    const float* b_i          = (const float*)d_in[6];
    const float* vals         = (const float*)d_in[7];
    const int*   rows         = (const int*)d_in[8];
    const int*   cols         = (const int*)d_in[9];
    const int*   pos_idx      = (const int*)d_in[10];
    const int*   neg_item_idx = (const int*)d_in[11];

    const int num_users  = in_sizes[5];
    const int num_movies = in_sizes[6];
    const int in_feats   = in_sizes[0] / num_movies;   // 128
    const int nnz        = in_sizes[7];
    const int num_pos    = in_sizes[10];
    const int S          = in_sizes[11] / num_pos;     // 5

    const int nbuckets = (num_users + BUCKET_W - 1) >> BUCKET_SHIFT;  // 782
    const int ntiles   = (nnz + TILE_E - 1) / TILE_E;                 // 245
    const int scanN    = nbuckets * ntiles;                           // 191590
    const int n1       = (scanN + 255) / 256;                         // 749
    const int n2       = (n1 + 255) / 256;                            // 3 (<=256)

    // workspace layout (256B-aligned)
    auto align256 = [](size_t x) { return (x + 255) & ~(size_t)255; };
    char* ws = (char*)d_ws;
    size_t off = 0;
    float* P        = (float*)(ws + off); off += align256((size_t)num_movies * HIDDEN * 4);
    float* Q        = (float*)(ws + off); off += align256((size_t)num_movies * HIDDEN * 4);
    float* H        = (float*)(ws + off); off += align256((size_t)num_movies * HIDDEN * 4);
    float* user_emb = (float*)(ws + off); off += align256((size_t)num_users * HIDDEN * 4);
    float* user_deg = (float*)(ws + off); off += align256((size_t)num_users * 4);
    unsigned* tileHist = (unsigned*)(ws + off); off += align256((size_t)scanN * 4);
    unsigned* offs     = (unsigned*)(ws + off); off += align256((size_t)(scanN + 1) * 4);
    unsigned* sums1    = (unsigned*)(ws + off); off += align256((size_t)n1 * 4);
    unsigned* top_off  = (unsigned*)(ws + off); off += align256(256 * 4);
    uint2* pairs    = (uint2*)(ws + off); off += align256((size_t)nnz * 8);

    float* out = (float*)d_out;
    hipMemsetAsync(out, 0, sizeof(float), stream);

    const int enc_blocks = (num_movies * 64 + 255) / 256;
    h_kernel<<<enc_blocks, 256, 0, stream>>>(features, W_enc, b_enc, H,
                                             num_movies, in_feats);
    pq_kernel<<<enc_blocks, 256, 0, stream>>>(H, W_p, W_q, P, Q, out, num_movies);

    const size_t hist_lds = (size_t)nbuckets * 4;
    tilehist_kernel<<<ntiles, 256, hist_lds, stream>>>(rows, nnz, nbuckets,
                                                       ntiles, tileHist);
    // 3-level exclusive scan of tileHist -> offs
    chunksum_kernel<<<n1, 256, 0, stream>>>(tileHist, scanN, sums1);
    chunksum_kernel<<<n2, 256, 0, stream>>>(sums1, n1, top_off + 0 /*reuse? no*/);
    // NOTE: second chunksum writes into top_off temporarily as sums2 (n2<=256)
    scantop_kernel<<<1, 256, 0, stream>>>(top_off, n2, top_off, offs, scanN, nnz);
    exscan_kernel<<<n2, 256, 0, stream>>>(sums1, n1, top_off, sums1);   // in-place
    exscan_kernel<<<n1, 256, 0, stream>>>(tileHist, scanN, sums1, offs);

    const size_t part_lds = (size_t)nbuckets * 8;  // hist + lofs
    partition_kernel<<<ntiles, 256, part_lds, stream>>>(rows, cols, vals, nnz,
                                                        nbuckets, ntiles, offs,
                                                        pairs);

    accumulate_kernel<<<nbuckets, 256, 0, stream>>>(pairs, offs, P, user_emb,
                                                    user_deg, num_users, ntiles);

    loss_kernel<<<(num_pos + 255) / 256, 256, 0, stream>>>(
        user_emb, user_deg, Q, b_u, b_i, rows, cols, pos_idx, neg_item_idx,
        num_pos, S, out);

    bias_reg_kernel<<<128, 256, 0, stream>>>(b_u, num_users, b_i, num_movies, out);
}

// Round 6
// 462.766 us; speedup vs baseline: 2.4672x; 2.4148x over previous
//
#include <hip/hip_runtime.h>

#define HIDDEN 64
#define BETA 0.01f
#define GAMMA 0.01f

#define BUCKET_SHIFT 8                 // 256 users per bucket
#define BUCKET_W     (1 << BUCKET_SHIFT)
#define TILE_E       8192              // entries per partition tile (32/thread)

// ---------------------------------------------------------------------------
// Encode phase A: H = features @ W_enc + b_enc   (thread per output element)
// ---------------------------------------------------------------------------
__global__ void h_kernel(const float* __restrict__ features,
                         const float* __restrict__ W_enc,
                         const float* __restrict__ b_enc,
                         float* __restrict__ H,
                         int num_movies, int in_feats) {
    const int tid = blockIdx.x * blockDim.x + threadIdx.x;
    const int j = tid & 63;
    const int m = tid >> 6;
    if (m >= num_movies) return;

    const float* frow = features + (size_t)m * in_feats;
    float a0 = 0.0f, a1 = 0.0f, a2 = 0.0f, a3 = 0.0f;
    #pragma unroll 8
    for (int f = 0; f < in_feats; f += 4) {
        const float4 fv = *(const float4*)(frow + f);
        a0 = fmaf(fv.x, W_enc[(f + 0) * HIDDEN + j], a0);
        a1 = fmaf(fv.y, W_enc[(f + 1) * HIDDEN + j], a1);
        a2 = fmaf(fv.z, W_enc[(f + 2) * HIDDEN + j], a2);
        a3 = fmaf(fv.w, W_enc[(f + 3) * HIDDEN + j], a3);
    }
    H[(size_t)m * HIDDEN + j] = (a0 + a1) + (a2 + a3) + b_enc[j];
}

// ---------------------------------------------------------------------------
// Encode phase B: P = H @ W_p, Q = H @ W_q + BETA regularizer.
// ---------------------------------------------------------------------------
__global__ void pq_kernel(const float* __restrict__ H,
                          const float* __restrict__ W_p,
                          const float* __restrict__ W_q,
                          float* __restrict__ P,
                          float* __restrict__ Q,
                          float* __restrict__ out_loss,
                          int num_movies) {
    const int tid = blockIdx.x * blockDim.x + threadIdx.x;
    const int j = tid & 63;
    const int m = tid >> 6;
    float reg = 0.0f;

    if (m < num_movies) {
        const float* hrow = H + (size_t)m * HIDDEN;
        float p0 = 0.0f, p1 = 0.0f, p2 = 0.0f, p3 = 0.0f;
        float q0 = 0.0f, q1 = 0.0f, q2 = 0.0f, q3 = 0.0f;
        #pragma unroll 4
        for (int f = 0; f < HIDDEN; f += 4) {
            const float4 hv = *(const float4*)(hrow + f);
            p0 = fmaf(hv.x, W_p[(f + 0) * HIDDEN + j], p0);
            p1 = fmaf(hv.y, W_p[(f + 1) * HIDDEN + j], p1);
            p2 = fmaf(hv.z, W_p[(f + 2) * HIDDEN + j], p2);
            p3 = fmaf(hv.w, W_p[(f + 3) * HIDDEN + j], p3);
            q0 = fmaf(hv.x, W_q[(f + 0) * HIDDEN + j], q0);
            q1 = fmaf(hv.y, W_q[(f + 1) * HIDDEN + j], q1);
            q2 = fmaf(hv.z, W_q[(f + 2) * HIDDEN + j], q2);
            q3 = fmaf(hv.w, W_q[(f + 3) * HIDDEN + j], q3);
        }
        const float p = (p0 + p1) + (p2 + p3);
        const float q = (q0 + q1) + (q2 + q3);
        P[(size_t)m * HIDDEN + j] = p;
        Q[(size_t)m * HIDDEN + j] = q;
        reg = p * p + q * q;
    }

    for (int off = 32; off; off >>= 1) reg += __shfl_down(reg, off);
    __shared__ float s_part[16];
    const int wave = threadIdx.x >> 6;
    const int lane = threadIdx.x & 63;
    if (lane == 0) s_part[wave] = reg;
    __syncthreads();
    if (threadIdx.x == 0) {
        float t = 0.0f;
        const int nw = blockDim.x >> 6;
        for (int w = 0; w < nw; ++w) t += s_part[w];
        atomicAdd(out_loss, 0.5f * BETA * t);
    }
}

// ---------------------------------------------------------------------------
// Fused histograms: per-tile LDS bucket histogram (tileHist[b*nT + t]) AND
// per-user global count (fire-and-forget int atomics, measured fast in r3).
// ---------------------------------------------------------------------------
__global__ void tilehist_kernel(const int* __restrict__ rows, int nnz,
                                int nbuckets, int ntiles,
                                unsigned* __restrict__ tileHist,
                                int* __restrict__ counts_u) {
    extern __shared__ unsigned hist[];          // nbuckets
    const int t = blockIdx.x;
    const int tid = threadIdx.x;
    for (int i = tid; i < nbuckets; i += blockDim.x) hist[i] = 0;
    __syncthreads();

    const int base = t * TILE_E;
    const int kmax = TILE_E / 256;
    for (int k = 0; k < kmax; ++k) {
        const int e = base + k * 256 + tid;
        if (e < nnz) {
            const int r = rows[e];
            atomicAdd(&hist[r >> BUCKET_SHIFT], 1u);
            atomicAdd(&counts_u[r], 1);         // fire-and-forget
        }
    }
    __syncthreads();
    for (int i = tid; i < nbuckets; i += blockDim.x)
        tileHist[(size_t)i * ntiles + t] = hist[i];
}

// ---------------------------------------------------------------------------
// Generic 2-level scan building blocks (n <= 256*256).
// ---------------------------------------------------------------------------
__global__ void chunksum_kernel(const unsigned* __restrict__ src, int n,
                                unsigned* __restrict__ sums) {
    __shared__ unsigned s[256];
    const int t = threadIdx.x;
    const int i = blockIdx.x * 256 + t;
    s[t] = (i < n) ? src[i] : 0u;
    __syncthreads();
    for (int off = 128; off; off >>= 1) {
        if (t < off) s[t] += s[t + off];
        __syncthreads();
    }
    if (t == 0) sums[blockIdx.x] = s[0];
}

// single-block exclusive scan of chunk sums (nchunks <= 256); also writes the
// guard slot offs[n] = total.
__global__ void scantop_kernel(const unsigned* __restrict__ sums, int nchunks,
                               unsigned* __restrict__ chunk_off,
                               unsigned* __restrict__ offs, int n, int total) {
    __shared__ unsigned s[256];
    const int t = threadIdx.x;
    unsigned x = (t < nchunks) ? sums[t] : 0u;
    s[t] = x;
    __syncthreads();
    for (int off = 1; off < 256; off <<= 1) {
        unsigned v = (t >= off) ? s[t - off] : 0u;
        __syncthreads();
        s[t] += v;
        __syncthreads();
    }
    if (t < nchunks) chunk_off[t] = s[t] - x;   // exclusive
    if (t == 0) offs[n] = (unsigned)total;
}

// per-chunk exclusive scan + chunk offset.
__global__ void exscan_kernel(const unsigned* __restrict__ src, int n,
                              const unsigned* __restrict__ chunk_off,
                              unsigned* __restrict__ dst) {
    __shared__ unsigned s[256];
    const int t = threadIdx.x;
    const int i = blockIdx.x * 256 + t;
    unsigned x = (i < n) ? src[i] : 0u;
    s[t] = x;
    __syncthreads();
    for (int off = 1; off < 256; off <<= 1) {
        unsigned v = (t >= off) ? s[t - off] : 0u;
        __syncthreads();
        s[t] += v;
        __syncthreads();
    }
    if (i < n) dst[i] = chunk_off[blockIdx.x] + s[t] - x;
}

// ---------------------------------------------------------------------------
// Partition level 1: scatter entries into bucket-major temp order.
// LDS returning atomics for rank; dst = offsB[b*nT + t] + lrank.
// Active write window per WG ~ 196 buckets x ~340B ~ 66 KB -> L2-resident.
// key = (user << 15) | col   (user<50000 -> 16b, col<32768 -> 15b, 31b total)
// ---------------------------------------------------------------------------
__global__ void partition_kernel(const int* __restrict__ rows,
                                 const int* __restrict__ cols,
                                 const float* __restrict__ vals, int nnz,
                                 int nbuckets, int ntiles,
                                 const unsigned* __restrict__ offsB,
                                 uint2* __restrict__ temp) {
    extern __shared__ unsigned smem[];          // hist[nb] then lofs[nb]
    unsigned* hist = smem;
    unsigned* lofs = smem + nbuckets;
    const int t = blockIdx.x;
    const int tid = threadIdx.x;
    for (int i = tid; i < nbuckets; i += blockDim.x) {
        hist[i] = 0;
        lofs[i] = offsB[(size_t)i * ntiles + t];
    }
    __syncthreads();

    const int base = t * TILE_E;
    const int kmax = TILE_E / 256;
    for (int k = 0; k < kmax; ++k) {
        const int e = base + k * 256 + tid;
        if (e < nnz) {
            const int r = rows[e];
            const int b = r >> BUCKET_SHIFT;
            const unsigned lrank = atomicAdd(&hist[b], 1u);
            const unsigned dst = lofs[b] + lrank;
            const unsigned key = ((unsigned)r << 15) | (unsigned)cols[e];
            temp[dst] = make_uint2(key, __float_as_uint(vals[e]));
        }
    }
}

// ---------------------------------------------------------------------------
// Partition level 2: per-bucket WG turns bucket-major temp into exact CSR.
// LDS cursors (256 users) init from row_start; coalesced read of bucket run;
// writes land inside the bucket's ~82 KB CSR window (L2-local).
// Output pair: (col, val_bits).
// ---------------------------------------------------------------------------
__global__ void csr_scatter_kernel(const uint2* __restrict__ temp,
                                   const unsigned* __restrict__ offsB,
                                   const int* __restrict__ row_start,
                                   uint2* __restrict__ pairs,
                                   int ntiles, int num_users) {
    __shared__ int cursors[BUCKET_W];
    const int b = blockIdx.x;
    const int tid = threadIdx.x;
    const int ubase = b << BUCKET_SHIFT;
    const int nu_local = min(BUCKET_W, num_users - ubase);
    if (tid < nu_local) cursors[tid] = row_start[ubase + tid];
    __syncthreads();

    const int s0 = (int)offsB[(size_t)b * ntiles];
    const int s1 = (int)offsB[(size_t)(b + 1) * ntiles];
    for (int s = s0 + tid; s < s1; s += 256) {
        const uint2 e = temp[s];
        const int lu = (int)(e.x >> 15) - ubase;
        const int dst = atomicAdd(&cursors[lu], 1);
        pairs[dst] = make_uint2(e.x & 0x7fffu, e.y);
    }
}

// ---------------------------------------------------------------------------
// Segment sum, gather style: one wave per user (50K waves of TLP),
// register accumulation, no atomics, 2x unroll.
// ---------------------------------------------------------------------------
__global__ void gather_kernel(const int* __restrict__ row_start,
                              const uint2* __restrict__ pairs,
                              const float* __restrict__ P,
                              float* __restrict__ user_emb,
                              float* __restrict__ user_deg, int nu) {
    const int lane  = threadIdx.x & 63;
    const int u = (blockIdx.x * blockDim.x + threadIdx.x) >> 6;
    if (u >= nu) return;

    const int s0 = row_start[u];
    const int s1 = row_start[u + 1];
    float acc0 = 0.0f, acc1 = 0.0f, deg = 0.0f;
    int s = s0;
    for (; s + 1 < s1; s += 2) {
        const uint2 pr0 = pairs[s];
        const uint2 pr1 = pairs[s + 1];
        const float v0 = __uint_as_float(pr0.y);
        const float v1 = __uint_as_float(pr1.y);
        acc0 = fmaf(v0, P[(size_t)pr0.x * HIDDEN + lane], acc0);
        acc1 = fmaf(v1, P[(size_t)pr1.x * HIDDEN + lane], acc1);
        deg += v0 + v1;
    }
    if (s < s1) {
        const uint2 pr = pairs[s];
        const float v = __uint_as_float(pr.y);
        acc0 = fmaf(v, P[(size_t)pr.x * HIDDEN + lane], acc0);
        deg += v;
    }
    user_emb[(size_t)u * HIDDEN + lane] = acc0 + acc1;
    if (lane == 0) user_deg[u] = deg;
}

// ---------------------------------------------------------------------------
// Pair loss. One thread per positive pair.
// ---------------------------------------------------------------------------
__global__ void loss_kernel(const float* __restrict__ user_emb,
                            const float* __restrict__ user_deg,
                            const float* __restrict__ Q,
                            const float* __restrict__ b_u,
                            const float* __restrict__ b_i,
                            const int* __restrict__ rows,
                            const int* __restrict__ cols,
                            const int* __restrict__ pos_idx,
                            const int* __restrict__ neg_item_idx,
                            int num_pos, int S,
                            float* __restrict__ out_loss) {
    const int p = blockIdx.x * blockDim.x + threadIdx.x;
    float acc = 0.0f;

    if (p < num_pos) {
        const int e = pos_idx[p];
        const int u = rows[e];
        const int ii = cols[e];
        const float invdeg = 1.0f / user_deg[u];

        float ue[HIDDEN];
        const float4* uep = (const float4*)(user_emb + (size_t)u * HIDDEN);
        #pragma unroll
        for (int k = 0; k < HIDDEN / 4; ++k) {
            float4 t4 = uep[k];
            ue[4 * k + 0] = t4.x * invdeg;
            ue[4 * k + 1] = t4.y * invdeg;
            ue[4 * k + 2] = t4.z * invdeg;
            ue[4 * k + 3] = t4.w * invdeg;
        }
        const float bu = b_u[u];

        const float4* qp = (const float4*)(Q + (size_t)ii * HIDDEN);
        float dot = 0.0f;
        #pragma unroll
        for (int k = 0; k < HIDDEN / 4; ++k) {
            float4 t4 = qp[k];
            dot = fmaf(ue[4 * k + 0], t4.x, dot);
            dot = fmaf(ue[4 * k + 1], t4.y, dot);
            dot = fmaf(ue[4 * k + 2], t4.z, dot);
            dot = fmaf(ue[4 * k + 3], t4.w, dot);
        }
        const float r = bu + b_i[ii] + dot;

        for (int s = 0; s < S; ++s) {
            const int j = neg_item_idx[(size_t)p * S + s];
            const float4* qn = (const float4*)(Q + (size_t)j * HIDDEN);
            float dn = 0.0f;
            #pragma unroll
            for (int k = 0; k < HIDDEN / 4; ++k) {
                float4 t4 = qn[k];
                dn = fmaf(ue[4 * k + 0], t4.x, dn);
                dn = fmaf(ue[4 * k + 1], t4.y, dn);
                dn = fmaf(ue[4 * k + 2], t4.z, dn);
                dn = fmaf(ue[4 * k + 3], t4.w, dn);
            }
            const float nr = bu + b_i[j] + dn;
            const float diff = 1.0f - (r - nr);
            acc += 0.5f * diff * diff;
        }
    }

    for (int off = 32; off; off >>= 1) acc += __shfl_down(acc, off);
    __shared__ float s_part[16];
    const int wave = threadIdx.x >> 6;
    const int lane = threadIdx.x & 63;
    if (lane == 0) s_part[wave] = acc;
    __syncthreads();
    if (threadIdx.x == 0) {
        float t = 0.0f;
        const int nw = blockDim.x >> 6;
        for (int w = 0; w < nw; ++w) t += s_part[w];
        atomicAdd(out_loss, t);
    }
}

// ---------------------------------------------------------------------------
// Bias regularizer 0.5*GAMMA*(sum b_u^2 + sum b_i^2)
// ---------------------------------------------------------------------------
__global__ void bias_reg_kernel(const float* __restrict__ b_u, int nu,
                                const float* __restrict__ b_i, int ni,
                                float* __restrict__ out_loss) {
    const int tid = blockIdx.x * blockDim.x + threadIdx.x;
    const int stride = gridDim.x * blockDim.x;
    const int n = nu + ni;
    float acc = 0.0f;
    for (int x = tid; x < n; x += stride) {
        float v = (x < nu) ? b_u[x] : b_i[x - nu];
        acc += v * v;
    }
    for (int off = 32; off; off >>= 1) acc += __shfl_down(acc, off);
    __shared__ float s_part[16];
    const int wave = threadIdx.x >> 6;
    const int lane = threadIdx.x & 63;
    if (lane == 0) s_part[wave] = acc;
    __syncthreads();
    if (threadIdx.x == 0) {
        float t = 0.0f;
        const int nw = blockDim.x >> 6;
        for (int w = 0; w < nw; ++w) t += s_part[w];
        atomicAdd(out_loss, 0.5f * GAMMA * t);
    }
}

// ---------------------------------------------------------------------------
extern "C" void kernel_launch(void* const* d_in, const int* in_sizes, int n_in,
                              void* d_out, int out_size, void* d_ws, size_t ws_size,
                              hipStream_t stream) {
    const float* features     = (const float*)d_in[0];
    const float* W_enc        = (const float*)d_in[1];
    const float* b_enc        = (const float*)d_in[2];
    const float* W_p          = (const float*)d_in[3];
    const float* W_q          = (const float*)d_in[4];
    const float* b_u          = (const float*)d_in[5];
    const float* b_i          = (const float*)d_in[6];
    const float* vals         = (const float*)d_in[7];
    const int*   rows         = (const int*)d_in[8];
    const int*   cols         = (const int*)d_in[9];
    const int*   pos_idx      = (const int*)d_in[10];
    const int*   neg_item_idx = (const int*)d_in[11];

    const int num_users  = in_sizes[5];                 // 50000
    const int num_movies = in_sizes[6];                 // 20000
    const int in_feats   = in_sizes[0] / num_movies;    // 128
    const int nnz        = in_sizes[7];                 // 2000000
    const int num_pos    = in_sizes[10];                // 200000
    const int S          = in_sizes[11] / num_pos;      // 5

    const int nbB    = (num_users + BUCKET_W - 1) >> BUCKET_SHIFT;  // 196
    const int ntiles = (nnz + TILE_E - 1) / TILE_E;                 // 245
    const int scanNB = nbB * ntiles;                                // 48020
    const int n1b    = (scanNB + 255) / 256;                        // 188 <= 256
    const int n1u    = (num_users + 255) / 256;                     // 196 <= 256

    // workspace layout (256B-aligned). Time-shared region U:
    //   H (d1-d2)  |  temp (d5-d10)  |  user_emb (d11+)  all sequential-safe.
    auto align256 = [](size_t x) { return (x + 255) & ~(size_t)255; };
    char* ws = (char*)d_ws;
    size_t off = 0;
    float* P = (float*)(ws + off); off += align256((size_t)num_movies * HIDDEN * 4);
    float* Q = (float*)(ws + off); off += align256((size_t)num_movies * HIDDEN * 4);
    char*  U = ws + off;
    const size_t h_bytes   = align256((size_t)num_movies * HIDDEN * 4);   // 5.12 MB
    const size_t emb_bytes = align256((size_t)num_users * HIDDEN * 4);    // 12.8 MB
    const size_t tmp_bytes = align256((size_t)nnz * 8);                   // 16 MB
    float* H        = (float*)U;
    float* user_emb = (float*)(U + h_bytes);
    uint2* temp     = (uint2*)U;
    off += (h_bytes + emb_bytes > tmp_bytes) ? (h_bytes + emb_bytes) : tmp_bytes;
    float* user_deg = (float*)(ws + off); off += align256((size_t)num_users * 4);
    int*   counts_u = (int*)(ws + off);   off += align256((size_t)num_users * 4);
    int*   row_start= (int*)(ws + off);   off += align256((size_t)(num_users + 1) * 4);
    unsigned* tileHistB = (unsigned*)(ws + off); off += align256((size_t)scanNB * 4);
    unsigned* offsB     = (unsigned*)(ws + off); off += align256((size_t)(scanNB + 1) * 4);
    unsigned* sums_u    = (unsigned*)(ws + off); off += align256(256 * 4);
    unsigned* top_u     = (unsigned*)(ws + off); off += align256(256 * 4);
    unsigned* sums_b    = (unsigned*)(ws + off); off += align256(256 * 4);
    unsigned* top_b     = (unsigned*)(ws + off); off += align256(256 * 4);
    uint2* pairs        = (uint2*)(ws + off);    off += align256((size_t)nnz * 8);

    float* out = (float*)d_out;
    hipMemsetAsync(out, 0, sizeof(float), stream);
    hipMemsetAsync(counts_u, 0, (size_t)num_users * 4, stream);

    // encode
    const int enc_blocks = (num_movies * 64 + 255) / 256;
    h_kernel<<<enc_blocks, 256, 0, stream>>>(features, W_enc, b_enc, H,
                                             num_movies, in_feats);
    pq_kernel<<<enc_blocks, 256, 0, stream>>>(H, W_p, W_q, P, Q, out, num_movies);

    // fused bucket-tile + user histograms
    tilehist_kernel<<<ntiles, 256, (size_t)nbB * 4, stream>>>(
        rows, nnz, nbB, ntiles, tileHistB, counts_u);

    // user-level scan: counts_u -> row_start (guard row_start[NU] = nnz)
    chunksum_kernel<<<n1u, 256, 0, stream>>>((const unsigned*)counts_u,
                                             num_users, sums_u);
    scantop_kernel<<<1, 256, 0, stream>>>(sums_u, n1u, top_u,
                                          (unsigned*)row_start, num_users, nnz);
    exscan_kernel<<<n1u, 256, 0, stream>>>((const unsigned*)counts_u, num_users,
                                           top_u, (unsigned*)row_start);

    // bucket-tile scan: tileHistB -> offsB (guard offsB[scanNB] = nnz)
    chunksum_kernel<<<n1b, 256, 0, stream>>>(tileHistB, scanNB, sums_b);
    scantop_kernel<<<1, 256, 0, stream>>>(sums_b, n1b, top_b, offsB, scanNB, nnz);
    exscan_kernel<<<n1b, 256, 0, stream>>>(tileHistB, scanNB, top_b, offsB);

    // two-level partition -> exact CSR pairs
    partition_kernel<<<ntiles, 256, (size_t)nbB * 8, stream>>>(
        rows, cols, vals, nnz, nbB, ntiles, offsB, temp);
    csr_scatter_kernel<<<nbB, 256, 0, stream>>>(temp, offsB, row_start, pairs,
                                                ntiles, num_users);

    // segment sum (register gather, 50K waves)
    gather_kernel<<<(num_users * 64 + 255) / 256, 256, 0, stream>>>(
        row_start, pairs, P, user_emb, user_deg, num_users);

    loss_kernel<<<(num_pos + 255) / 256, 256, 0, stream>>>(
        user_emb, user_deg, Q, b_u, b_i, rows, cols, pos_idx, neg_item_idx,
        num_pos, S, out);

    bias_reg_kernel<<<128, 256, 0, stream>>>(b_u, num_users, b_i, num_movies, out);
}

// Round 7
// 429.321 us; speedup vs baseline: 2.6594x; 1.0779x over previous
//
#include <hip/hip_runtime.h>

#define HIDDEN 64
#define BETA 0.01f
#define GAMMA 0.01f

#define BUCKET_SHIFT 8                 // 256 users per bucket
#define BUCKET_W     (1 << BUCKET_SHIFT)
#define TILE_E       8192              // entries per partition tile (32/thread)

// ---------------------------------------------------------------------------
// Encode phase A: H = features @ W_enc + b_enc   (thread per output element)
// ---------------------------------------------------------------------------
__global__ void h_kernel(const float* __restrict__ features,
                         const float* __restrict__ W_enc,
                         const float* __restrict__ b_enc,
                         float* __restrict__ H,
                         int num_movies, int in_feats) {
    const int tid = blockIdx.x * blockDim.x + threadIdx.x;
    const int j = tid & 63;
    const int m = tid >> 6;
    if (m >= num_movies) return;

    const float* frow = features + (size_t)m * in_feats;
    float a0 = 0.0f, a1 = 0.0f, a2 = 0.0f, a3 = 0.0f;
    #pragma unroll 8
    for (int f = 0; f < in_feats; f += 4) {
        const float4 fv = *(const float4*)(frow + f);
        a0 = fmaf(fv.x, W_enc[(f + 0) * HIDDEN + j], a0);
        a1 = fmaf(fv.y, W_enc[(f + 1) * HIDDEN + j], a1);
        a2 = fmaf(fv.z, W_enc[(f + 2) * HIDDEN + j], a2);
        a3 = fmaf(fv.w, W_enc[(f + 3) * HIDDEN + j], a3);
    }
    H[(size_t)m * HIDDEN + j] = (a0 + a1) + (a2 + a3) + b_enc[j];
}

// ---------------------------------------------------------------------------
// Encode phase B: P = H @ W_p, Q = H @ W_q + BETA regularizer.
// ---------------------------------------------------------------------------
__global__ void pq_kernel(const float* __restrict__ H,
                          const float* __restrict__ W_p,
                          const float* __restrict__ W_q,
                          float* __restrict__ P,
                          float* __restrict__ Q,
                          float* __restrict__ out_loss,
                          int num_movies) {
    const int tid = blockIdx.x * blockDim.x + threadIdx.x;
    const int j = tid & 63;
    const int m = tid >> 6;
    float reg = 0.0f;

    if (m < num_movies) {
        const float* hrow = H + (size_t)m * HIDDEN;
        float p0 = 0.0f, p1 = 0.0f, p2 = 0.0f, p3 = 0.0f;
        float q0 = 0.0f, q1 = 0.0f, q2 = 0.0f, q3 = 0.0f;
        #pragma unroll 4
        for (int f = 0; f < HIDDEN; f += 4) {
            const float4 hv = *(const float4*)(hrow + f);
            p0 = fmaf(hv.x, W_p[(f + 0) * HIDDEN + j], p0);
            p1 = fmaf(hv.y, W_p[(f + 1) * HIDDEN + j], p1);
            p2 = fmaf(hv.z, W_p[(f + 2) * HIDDEN + j], p2);
            p3 = fmaf(hv.w, W_p[(f + 3) * HIDDEN + j], p3);
            q0 = fmaf(hv.x, W_q[(f + 0) * HIDDEN + j], q0);
            q1 = fmaf(hv.y, W_q[(f + 1) * HIDDEN + j], q1);
            q2 = fmaf(hv.z, W_q[(f + 2) * HIDDEN + j], q2);
            q3 = fmaf(hv.w, W_q[(f + 3) * HIDDEN + j], q3);
        }
        const float p = (p0 + p1) + (p2 + p3);
        const float q = (q0 + q1) + (q2 + q3);
        P[(size_t)m * HIDDEN + j] = p;
        Q[(size_t)m * HIDDEN + j] = q;
        reg = p * p + q * q;
    }

    for (int off = 32; off; off >>= 1) reg += __shfl_down(reg, off);
    __shared__ float s_part[16];
    const int wave = threadIdx.x >> 6;
    const int lane = threadIdx.x & 63;
    if (lane == 0) s_part[wave] = reg;
    __syncthreads();
    if (threadIdx.x == 0) {
        float t = 0.0f;
        const int nw = blockDim.x >> 6;
        for (int w = 0; w < nw; ++w) t += s_part[w];
        atomicAdd(out_loss, 0.5f * BETA * t);
    }
}

// ---------------------------------------------------------------------------
// Per-tile LDS bucket histogram only (user counts now derived in csr_scatter).
// ---------------------------------------------------------------------------
__global__ void tilehist_kernel(const int* __restrict__ rows, int nnz,
                                int nbuckets, int ntiles,
                                unsigned* __restrict__ tileHist) {
    extern __shared__ unsigned hist[];          // nbuckets
    const int t = blockIdx.x;
    const int tid = threadIdx.x;
    for (int i = tid; i < nbuckets; i += blockDim.x) hist[i] = 0;
    __syncthreads();

    const int base = t * TILE_E;
    const int kmax = TILE_E / 256;
    for (int k = 0; k < kmax; ++k) {
        const int e = base + k * 256 + tid;
        if (e < nnz) atomicAdd(&hist[rows[e] >> BUCKET_SHIFT], 1u);
    }
    __syncthreads();
    for (int i = tid; i < nbuckets; i += blockDim.x)
        tileHist[(size_t)i * ntiles + t] = hist[i];
}

// ---------------------------------------------------------------------------
// Generic 2-level scan building blocks (n <= 256*256).
// ---------------------------------------------------------------------------
__global__ void chunksum_kernel(const unsigned* __restrict__ src, int n,
                                unsigned* __restrict__ sums) {
    __shared__ unsigned s[256];
    const int t = threadIdx.x;
    const int i = blockIdx.x * 256 + t;
    s[t] = (i < n) ? src[i] : 0u;
    __syncthreads();
    for (int off = 128; off; off >>= 1) {
        if (t < off) s[t] += s[t + off];
        __syncthreads();
    }
    if (t == 0) sums[blockIdx.x] = s[0];
}

__global__ void scantop_kernel(const unsigned* __restrict__ sums, int nchunks,
                               unsigned* __restrict__ chunk_off,
                               unsigned* __restrict__ offs, int n, int total) {
    __shared__ unsigned s[256];
    const int t = threadIdx.x;
    unsigned x = (t < nchunks) ? sums[t] : 0u;
    s[t] = x;
    __syncthreads();
    for (int off = 1; off < 256; off <<= 1) {
        unsigned v = (t >= off) ? s[t - off] : 0u;
        __syncthreads();
        s[t] += v;
        __syncthreads();
    }
    if (t < nchunks) chunk_off[t] = s[t] - x;   // exclusive
    if (t == 0) offs[n] = (unsigned)total;
}

__global__ void exscan_kernel(const unsigned* __restrict__ src, int n,
                              const unsigned* __restrict__ chunk_off,
                              unsigned* __restrict__ dst) {
    __shared__ unsigned s[256];
    const int t = threadIdx.x;
    const int i = blockIdx.x * 256 + t;
    unsigned x = (i < n) ? src[i] : 0u;
    s[t] = x;
    __syncthreads();
    for (int off = 1; off < 256; off <<= 1) {
        unsigned v = (t >= off) ? s[t - off] : 0u;
        __syncthreads();
        s[t] += v;
        __syncthreads();
    }
    if (i < n) dst[i] = chunk_off[blockIdx.x] + s[t] - x;
}

// ---------------------------------------------------------------------------
// Partition level 1: scatter entries into bucket-major temp order.
// key = (user << 15) | col
// ---------------------------------------------------------------------------
__global__ void partition_kernel(const int* __restrict__ rows,
                                 const int* __restrict__ cols,
                                 const float* __restrict__ vals, int nnz,
                                 int nbuckets, int ntiles,
                                 const unsigned* __restrict__ offsB,
                                 uint2* __restrict__ temp) {
    extern __shared__ unsigned smem[];          // hist[nb] then lofs[nb]
    unsigned* hist = smem;
    unsigned* lofs = smem + nbuckets;
    const int t = blockIdx.x;
    const int tid = threadIdx.x;
    for (int i = tid; i < nbuckets; i += blockDim.x) {
        hist[i] = 0;
        lofs[i] = offsB[(size_t)i * ntiles + t];
    }
    __syncthreads();

    const int base = t * TILE_E;
    const int kmax = TILE_E / 256;
    for (int k = 0; k < kmax; ++k) {
        const int e = base + k * 256 + tid;
        if (e < nnz) {
            const int r = rows[e];
            const int b = r >> BUCKET_SHIFT;
            const unsigned lrank = atomicAdd(&hist[b], 1u);
            const unsigned dst = lofs[b] + lrank;
            const unsigned key = ((unsigned)r << 15) | (unsigned)cols[e];
            temp[dst] = make_uint2(key, __float_as_uint(vals[e]));
        }
    }
}

// ---------------------------------------------------------------------------
// Partition level 2 (FUSED with per-user counting): per-bucket WG.
// Pass 1: count entries per local user (LDS). Exclusive 256-scan in LDS ->
// row_start written directly. Pass 2: scatter into exact CSR slots via LDS
// cursors. temp run (~82 KB) stays L2-hot between passes.
// ---------------------------------------------------------------------------
__global__ void csr_scatter_kernel(const uint2* __restrict__ temp,
                                   const unsigned* __restrict__ offsB,
                                   int* __restrict__ row_start,
                                   uint2* __restrict__ pairs,
                                   int ntiles, int num_users, int nbB) {
    __shared__ int cnt[BUCKET_W];
    __shared__ int scan_s[BUCKET_W];
    __shared__ int cur[BUCKET_W];
    const int b = blockIdx.x;
    const int tid = threadIdx.x;
    const int ubase = b << BUCKET_SHIFT;
    const int s0 = (int)offsB[(size_t)b * ntiles];
    const int s1 = (int)offsB[(size_t)(b + 1) * ntiles];

    cnt[tid] = 0;
    __syncthreads();
    for (int s = s0 + tid; s < s1; s += 256)
        atomicAdd(&cnt[(int)(temp[s].x >> 15) - ubase], 1);
    __syncthreads();

    // exclusive scan of cnt[0..255]
    const int x = cnt[tid];
    scan_s[tid] = x;
    __syncthreads();
    for (int off = 1; off < 256; off <<= 1) {
        int v = (tid >= off) ? scan_s[tid - off] : 0;
        __syncthreads();
        scan_s[tid] += v;
        __syncthreads();
    }
    const int start = s0 + scan_s[tid] - x;
    cur[tid] = start;
    if (ubase + tid < num_users) row_start[ubase + tid] = start;
    if (b == nbB - 1 && tid == 0) row_start[num_users] = s1;
    __syncthreads();

    for (int s = s0 + tid; s < s1; s += 256) {
        const uint2 e = temp[s];
        const int lu = (int)(e.x >> 15) - ubase;
        const int dst = atomicAdd(&cur[lu], 1);
        pairs[dst] = make_uint2(e.x & 0x7fffu, e.y);
    }
}

// ---------------------------------------------------------------------------
// Segment sum, gather style: one wave per user, register accumulation,
// 4x unroll for MLP (4 independent pairs+P-row load chains in flight).
// ---------------------------------------------------------------------------
__global__ void gather_kernel(const int* __restrict__ row_start,
                              const uint2* __restrict__ pairs,
                              const float* __restrict__ P,
                              float* __restrict__ user_emb,
                              float* __restrict__ user_deg, int nu) {
    const int lane = threadIdx.x & 63;
    const int u = (blockIdx.x * blockDim.x + threadIdx.x) >> 6;
    if (u >= nu) return;

    const int s0 = row_start[u];
    const int s1 = row_start[u + 1];
    float acc0 = 0.0f, acc1 = 0.0f, acc2 = 0.0f, acc3 = 0.0f, deg = 0.0f;
    int s = s0;
    for (; s + 3 < s1; s += 4) {
        const uint2 pr0 = pairs[s];
        const uint2 pr1 = pairs[s + 1];
        const uint2 pr2 = pairs[s + 2];
        const uint2 pr3 = pairs[s + 3];
        const float v0 = __uint_as_float(pr0.y);
        const float v1 = __uint_as_float(pr1.y);
        const float v2 = __uint_as_float(pr2.y);
        const float v3 = __uint_as_float(pr3.y);
        acc0 = fmaf(v0, P[(size_t)pr0.x * HIDDEN + lane], acc0);
        acc1 = fmaf(v1, P[(size_t)pr1.x * HIDDEN + lane], acc1);
        acc2 = fmaf(v2, P[(size_t)pr2.x * HIDDEN + lane], acc2);
        acc3 = fmaf(v3, P[(size_t)pr3.x * HIDDEN + lane], acc3);
        deg += (v0 + v1) + (v2 + v3);
    }
    for (; s < s1; ++s) {
        const uint2 pr = pairs[s];
        const float v = __uint_as_float(pr.y);
        acc0 = fmaf(v, P[(size_t)pr.x * HIDDEN + lane], acc0);
        deg += v;
    }
    user_emb[(size_t)u * HIDDEN + lane] = (acc0 + acc1) + (acc2 + acc3);
    if (lane == 0) user_deg[u] = deg;
}

// ---------------------------------------------------------------------------
// Pair loss, 16-lane group per pair: lane l holds float4 components
// [4l, 4l+4) of the 64-wide rows -> fully coalesced ue/Q loads.
// Dots reduced via 4-step __shfl_xor within the group. S compile-time.
// ---------------------------------------------------------------------------
template <int S>
__global__ void loss_kernel(const float* __restrict__ user_emb,
                            const float* __restrict__ user_deg,
                            const float* __restrict__ Q,
                            const float* __restrict__ b_u,
                            const float* __restrict__ b_i,
                            const int* __restrict__ rows,
                            const int* __restrict__ cols,
                            const int* __restrict__ pos_idx,
                            const int* __restrict__ neg_item_idx,
                            int num_pos,
                            float* __restrict__ out_loss) {
    const int tid = blockIdx.x * blockDim.x + threadIdx.x;
    const int g = tid >> 4;            // pair index
    const int l = tid & 15;            // lane within group
    float acc = 0.0f;

    if (g < num_pos) {
        const int e = pos_idx[g];
        const int u = rows[e];
        const int ii = cols[e];
        const float invdeg = 1.0f / user_deg[u];

        float4 ue = ((const float4*)(user_emb + (size_t)u * HIDDEN))[l];
        ue.x *= invdeg; ue.y *= invdeg; ue.z *= invdeg; ue.w *= invdeg;

        float part[1 + S];
        int jarr[S];
        {
            const float4 qv = ((const float4*)(Q + (size_t)ii * HIDDEN))[l];
            part[0] = fmaf(ue.x, qv.x, fmaf(ue.y, qv.y,
                      fmaf(ue.z, qv.z, ue.w * qv.w)));
        }
        #pragma unroll
        for (int s = 0; s < S; ++s) {
            const int j = neg_item_idx[(size_t)g * S + s];
            jarr[s] = j;
            const float4 qv = ((const float4*)(Q + (size_t)j * HIDDEN))[l];
            part[1 + s] = fmaf(ue.x, qv.x, fmaf(ue.y, qv.y,
                          fmaf(ue.z, qv.z, ue.w * qv.w)));
        }
        // group-wide reduction of all S+1 partials
        #pragma unroll
        for (int m = 1; m < 16; m <<= 1) {
            #pragma unroll
            for (int k = 0; k < 1 + S; ++k)
                part[k] += __shfl_xor(part[k], m, 16);
        }

        if (l == 0) {
            const float bu = b_u[u];
            const float r = bu + b_i[ii] + part[0];
            #pragma unroll
            for (int s = 0; s < S; ++s) {
                const float nr = bu + b_i[jarr[s]] + part[1 + s];
                const float diff = 1.0f - (r - nr);
                acc += 0.5f * diff * diff;
            }
        }
    }

    for (int off = 32; off; off >>= 1) acc += __shfl_down(acc, off);
    __shared__ float s_part[16];
    const int wave = threadIdx.x >> 6;
    const int lane = threadIdx.x & 63;
    if (lane == 0) s_part[wave] = acc;
    __syncthreads();
    if (threadIdx.x == 0) {
        float t = 0.0f;
        const int nw = blockDim.x >> 6;
        for (int w = 0; w < nw; ++w) t += s_part[w];
        atomicAdd(out_loss, t);
    }
}

// generic fallback (thread per pair), only used if S != 5
__global__ void loss_generic_kernel(const float* __restrict__ user_emb,
                                    const float* __restrict__ user_deg,
                                    const float* __restrict__ Q,
                                    const float* __restrict__ b_u,
                                    const float* __restrict__ b_i,
                                    const int* __restrict__ rows,
                                    const int* __restrict__ cols,
                                    const int* __restrict__ pos_idx,
                                    const int* __restrict__ neg_item_idx,
                                    int num_pos, int S,
                                    float* __restrict__ out_loss) {
    const int p = blockIdx.x * blockDim.x + threadIdx.x;
    float acc = 0.0f;
    if (p < num_pos) {
        const int e = pos_idx[p];
        const int u = rows[e];
        const int ii = cols[e];
        const float invdeg = 1.0f / user_deg[u];
        float ue[HIDDEN];
        const float4* uep = (const float4*)(user_emb + (size_t)u * HIDDEN);
        #pragma unroll
        for (int k = 0; k < HIDDEN / 4; ++k) {
            float4 t4 = uep[k];
            ue[4 * k + 0] = t4.x * invdeg; ue[4 * k + 1] = t4.y * invdeg;
            ue[4 * k + 2] = t4.z * invdeg; ue[4 * k + 3] = t4.w * invdeg;
        }
        const float bu = b_u[u];
        const float4* qp = (const float4*)(Q + (size_t)ii * HIDDEN);
        float dot = 0.0f;
        #pragma unroll
        for (int k = 0; k < HIDDEN / 4; ++k) {
            float4 t4 = qp[k];
            dot = fmaf(ue[4 * k], t4.x, fmaf(ue[4 * k + 1], t4.y,
                  fmaf(ue[4 * k + 2], t4.z, fmaf(ue[4 * k + 3], t4.w, dot))));
        }
        const float r = bu + b_i[ii] + dot;
        for (int s = 0; s < S; ++s) {
            const int j = neg_item_idx[(size_t)p * S + s];
            const float4* qn = (const float4*)(Q + (size_t)j * HIDDEN);
            float dn = 0.0f;
            #pragma unroll
            for (int k = 0; k < HIDDEN / 4; ++k) {
                float4 t4 = qn[k];
                dn = fmaf(ue[4 * k], t4.x, fmaf(ue[4 * k + 1], t4.y,
                     fmaf(ue[4 * k + 2], t4.z, fmaf(ue[4 * k + 3], t4.w, dn))));
            }
            const float nr = bu + b_i[j] + dn;
            const float diff = 1.0f - (r - nr);
            acc += 0.5f * diff * diff;
        }
    }
    for (int off = 32; off; off >>= 1) acc += __shfl_down(acc, off);
    __shared__ float s_part[16];
    const int wave = threadIdx.x >> 6;
    const int lane = threadIdx.x & 63;
    if (lane == 0) s_part[wave] = acc;
    __syncthreads();
    if (threadIdx.x == 0) {
        float t = 0.0f;
        const int nw = blockDim.x >> 6;
        for (int w = 0; w < nw; ++w) t += s_part[w];
        atomicAdd(out_loss, t);
    }
}

// ---------------------------------------------------------------------------
// Bias regularizer 0.5*GAMMA*(sum b_u^2 + sum b_i^2)
// ---------------------------------------------------------------------------
__global__ void bias_reg_kernel(const float* __restrict__ b_u, int nu,
                                const float* __restrict__ b_i, int ni,
                                float* __restrict__ out_loss) {
    const int tid = blockIdx.x * blockDim.x + threadIdx.x;
    const int stride = gridDim.x * blockDim.x;
    const int n = nu + ni;
    float acc = 0.0f;
    for (int x = tid; x < n; x += stride) {
        float v = (x < nu) ? b_u[x] : b_i[x - nu];
        acc += v * v;
    }
    for (int off = 32; off; off >>= 1) acc += __shfl_down(acc, off);
    __shared__ float s_part[16];
    const int wave = threadIdx.x >> 6;
    const int lane = threadIdx.x & 63;
    if (lane == 0) s_part[wave] = acc;
    __syncthreads();
    if (threadIdx.x == 0) {
        float t = 0.0f;
        const int nw = blockDim.x >> 6;
        for (int w = 0; w < nw; ++w) t += s_part[w];
        atomicAdd(out_loss, 0.5f * GAMMA * t);
    }
}

// ---------------------------------------------------------------------------
extern "C" void kernel_launch(void* const* d_in, const int* in_sizes, int n_in,
                              void* d_out, int out_size, void* d_ws, size_t ws_size,
                              hipStream_t stream) {
    const float* features     = (const float*)d_in[0];
    const float* W_enc        = (const float*)d_in[1];
    const float* b_enc        = (const float*)d_in[2];
    const float* W_p          = (const float*)d_in[3];
    const float* W_q          = (const float*)d_in[4];
    const float* b_u          = (const float*)d_in[5];
    const float* b_i          = (const float*)d_in[6];
    const float* vals         = (const float*)d_in[7];
    const int*   rows         = (const int*)d_in[8];
    const int*   cols         = (const int*)d_in[9];
    const int*   pos_idx      = (const int*)d_in[10];
    const int*   neg_item_idx = (const int*)d_in[11];

    const int num_users  = in_sizes[5];                 // 50000
    const int num_movies = in_sizes[6];                 // 20000
    const int in_feats   = in_sizes[0] / num_movies;    // 128
    const int nnz        = in_sizes[7];                 // 2000000
    const int num_pos    = in_sizes[10];                // 200000
    const int S          = in_sizes[11] / num_pos;      // 5

    const int nbB    = (num_users + BUCKET_W - 1) >> BUCKET_SHIFT;  // 196
    const int ntiles = (nnz + TILE_E - 1) / TILE_E;                 // 245
    const int scanNB = nbB * ntiles;                                // 48020
    const int n1b    = (scanNB + 255) / 256;                        // 188 <= 256

    // workspace layout (256B-aligned). Time-shared region U:
    //   H (encode) | temp (partition) | user_emb (gather+loss)
    auto align256 = [](size_t x) { return (x + 255) & ~(size_t)255; };
    char* ws = (char*)d_ws;
    size_t off = 0;
    float* P = (float*)(ws + off); off += align256((size_t)num_movies * HIDDEN * 4);
    float* Q = (float*)(ws + off); off += align256((size_t)num_movies * HIDDEN * 4);
    char*  U = ws + off;
    const size_t h_bytes   = align256((size_t)num_movies * HIDDEN * 4);   // 5.12 MB
    const size_t emb_bytes = align256((size_t)num_users * HIDDEN * 4);    // 12.8 MB
    const size_t tmp_bytes = align256((size_t)nnz * 8);                   // 16 MB
    float* H        = (float*)U;
    float* user_emb = (float*)(U + h_bytes);
    uint2* temp     = (uint2*)U;
    off += (h_bytes + emb_bytes > tmp_bytes) ? (h_bytes + emb_bytes) : tmp_bytes;
    float* user_deg = (float*)(ws + off); off += align256((size_t)num_users * 4);
    int*   row_start= (int*)(ws + off);   off += align256((size_t)(num_users + 1) * 4);
    unsigned* tileHistB = (unsigned*)(ws + off); off += align256((size_t)scanNB * 4);
    unsigned* offsB     = (unsigned*)(ws + off); off += align256((size_t)(scanNB + 1) * 4);
    unsigned* sums_b    = (unsigned*)(ws + off); off += align256(256 * 4);
    unsigned* top_b     = (unsigned*)(ws + off); off += align256(256 * 4);
    uint2* pairs        = (uint2*)(ws + off);    off += align256((size_t)nnz * 8);

    float* out = (float*)d_out;
    hipMemsetAsync(out, 0, sizeof(float), stream);

    // encode
    const int enc_blocks = (num_movies * 64 + 255) / 256;
    h_kernel<<<enc_blocks, 256, 0, stream>>>(features, W_enc, b_enc, H,
                                             num_movies, in_feats);
    pq_kernel<<<enc_blocks, 256, 0, stream>>>(H, W_p, W_q, P, Q, out, num_movies);

    // bucket-tile histogram + scan -> offsB
    tilehist_kernel<<<ntiles, 256, (size_t)nbB * 4, stream>>>(
        rows, nnz, nbB, ntiles, tileHistB);
    chunksum_kernel<<<n1b, 256, 0, stream>>>(tileHistB, scanNB, sums_b);
    scantop_kernel<<<1, 256, 0, stream>>>(sums_b, n1b, top_b, offsB, scanNB, nnz);
    exscan_kernel<<<n1b, 256, 0, stream>>>(tileHistB, scanNB, top_b, offsB);

    // two-level partition -> exact CSR pairs (+ row_start, fused)
    partition_kernel<<<ntiles, 256, (size_t)nbB * 8, stream>>>(
        rows, cols, vals, nnz, nbB, ntiles, offsB, temp);
    csr_scatter_kernel<<<nbB, 256, 0, stream>>>(temp, offsB, row_start, pairs,
                                                ntiles, num_users, nbB);

    // segment sum (register gather, 50K waves, 4x MLP)
    gather_kernel<<<(num_users * 64 + 255) / 256, 256, 0, stream>>>(
        row_start, pairs, P, user_emb, user_deg, num_users);

    if (S == 5) {
        loss_kernel<5><<<((size_t)num_pos * 16 + 255) / 256, 256, 0, stream>>>(
            user_emb, user_deg, Q, b_u, b_i, rows, cols, pos_idx, neg_item_idx,
            num_pos, out);
    } else {
        loss_generic_kernel<<<(num_pos + 255) / 256, 256, 0, stream>>>(
            user_emb, user_deg, Q, b_u, b_i, rows, cols, pos_idx, neg_item_idx,
            num_pos, S, out);
    }

    bias_reg_kernel<<<128, 256, 0, stream>>>(b_u, num_users, b_i, num_movies, out);
}